// Round 4
// baseline (254.214 us; speedup 1.0000x reference)
//
#include <hip/hip_runtime.h>
#include <hip/hip_bf16.h>
#include <stdint.h>

typedef __bf16 bf16x8 __attribute__((ext_vector_type(8)));
typedef float  f32x4  __attribute__((ext_vector_type(4)));
typedef unsigned short ushort8 __attribute__((ext_vector_type(8)));

#define DEVI static __device__ __forceinline__

static constexpr int TB  = 2;     // batch
static constexpr int TT  = 2048;  // seq len
static constexpr int TC  = 1024;  // d_model
static constexpr int TH  = 16;    // heads
static constexpr int THD = 64;    // head dim
static constexpr int TM  = TB * TT;  // 4096 flattened rows

DEVI unsigned short f2bu(float f) {
  union { float f; unsigned u; } v; v.f = f;
  unsigned u = v.u;
  return (unsigned short)((u + 0x7FFFu + ((u >> 16) & 1u)) >> 16);
}

DEVI void gload_lds16(const unsigned short* g, char* l) {
  __builtin_amdgcn_global_load_lds((const __attribute__((address_space(1))) void*)g,
                                   (__attribute__((address_space(3))) void*)l, 16, 0, 0);
}

// ---------------- cast fp32 -> bf16 (8 elems/thread) ----------------
__global__ void cast_bf16_kernel(const float* __restrict__ in, unsigned short* __restrict__ out, int n8) {
  int i = blockIdx.x * blockDim.x + threadIdx.x;
  if (i >= n8) return;
  float4 a = ((const float4*)in)[2 * i];
  float4 b = ((const float4*)in)[2 * i + 1];
  ushort8 r;
  r[0] = f2bu(a.x); r[1] = f2bu(a.y); r[2] = f2bu(a.z); r[3] = f2bu(a.w);
  r[4] = f2bu(b.x); r[5] = f2bu(b.y); r[6] = f2bu(b.z); r[7] = f2bu(b.w);
  ((ushort8*)out)[i] = r;
}

// ------------- transpose + cast: in fp32 [R][Cc] -> out bf16 [Cc][R] -------------
__global__ void transpose_cast_kernel(const float* __restrict__ in, unsigned short* __restrict__ out,
                                      int R, int Cc) {
  __shared__ float tile[32][33];
  const int c0 = blockIdx.x * 32, r0 = blockIdx.y * 32;
  const int tx = threadIdx.x, ty = threadIdx.y;  // (32, 8)
#pragma unroll
  for (int i = 0; i < 4; ++i)
    tile[ty + i * 8][tx] = in[(size_t)(r0 + ty + i * 8) * Cc + c0 + tx];
  __syncthreads();
#pragma unroll
  for (int i = 0; i < 4; ++i)
    out[(size_t)(c0 + ty + i * 8) * R + r0 + tx] = f2bu(tile[tx][ty + i * 8]);
}

// ------------- per-head V transpose: Vh[b][h][t][d] -> Vt[b][h][d][t] (bf16) -------------
__global__ void transpose_v_kernel(const unsigned short* __restrict__ Vh, unsigned short* __restrict__ Vt) {
  __shared__ unsigned short tile[64][72];  // 64 t-rows x 64 d-cols, padded row (144B)
  const int t0 = blockIdx.x * 64;
  const size_t ho = (size_t)(blockIdx.z * TH + blockIdx.y) * TT * THD;
  const int tid = threadIdx.x;  // 256
#pragma unroll
  for (int it = 0; it < 2; ++it) {
    const int r = it * 32 + (tid >> 3), c8 = tid & 7;
    *(ushort8*)&tile[r][c8 * 8] = *(const ushort8*)(Vh + ho + (size_t)(t0 + r) * THD + c8 * 8);
  }
  __syncthreads();
  const int d = tid >> 2, tc = tid & 3;
  ushort8 a, b;
#pragma unroll
  for (int j = 0; j < 8; ++j) a[j] = tile[tc * 16 + j][d];
#pragma unroll
  for (int j = 0; j < 8; ++j) b[j] = tile[tc * 16 + 8 + j][d];
  *(ushort8*)(Vt + ho + (size_t)d * TT + t0 + tc * 16) = a;
  *(ushort8*)(Vt + ho + (size_t)d * TT + t0 + tc * 16 + 8) = b;
}

// ---------------- GEMM: A[M][K] @ Bt[N][K]^T, bf16 MFMA, 128x128 tile ----------------
// EPI==0: write fp32 C[M][N].  EPI==1: scatter qkv -> per-head Q(,*0.125)/K/V [b][h][t][d].
template <int EPI>
__launch_bounds__(256)
__global__ void gemm_bt_kernel(const unsigned short* __restrict__ A, const unsigned short* __restrict__ Bt,
                               float* __restrict__ Cf,
                               unsigned short* __restrict__ Qo, unsigned short* __restrict__ Ko,
                               unsigned short* __restrict__ Vo,
                               int Mm, int Nn, int Kk) {
  __shared__ __align__(16) char smem[32768];
  char* ldsA = smem;
  char* ldsB = smem + 16384;
  const int tid = threadIdx.x;
  const int lane = tid & 63;
  const int wave = tid >> 6;
  const int l15 = lane & 15, l4 = lane >> 4;
  const int m0 = blockIdx.y * 128;
  const int n0 = blockIdx.x * 128;
  const int wm = (wave >> 1) * 64;
  const int wn = (wave & 1) * 64;

  f32x4 acc[4][4];
#pragma unroll
  for (int a = 0; a < 4; ++a)
#pragma unroll
    for (int b = 0; b < 4; ++b) acc[a][b] = (f32x4){0.f, 0.f, 0.f, 0.f};

  const int nk = Kk >> 6;
  for (int kt = 0; kt < nk; ++kt) {
    __syncthreads();  // previous tile fully consumed
#pragma unroll
    for (int r = 0; r < 4; ++r) {
      // LDS chunk cid holds global k-chunk (cid&7)^(row&7)  (XOR swizzle via pre-permuted source)
      const int cid = r * 256 + tid;
      const int row = cid >> 3;
      const int srcc = (cid & 7) ^ (row & 7);
      gload_lds16(A + (size_t)(m0 + row) * Kk + kt * 64 + srcc * 8, ldsA + (r * 256 + wave * 64) * 16);
      gload_lds16(Bt + (size_t)(n0 + row) * Kk + kt * 64 + srcc * 8, ldsB + (r * 256 + wave * 64) * 16);
    }
    __syncthreads();  // drains vmcnt -> tiles resident
#pragma unroll
    for (int ks = 0; ks < 2; ++ks) {
      bf16x8 af[4], bfv[4];
#pragma unroll
      for (int mf = 0; mf < 4; ++mf) {
        const int row = wm + mf * 16 + l15;
        const int ch = (ks * 4 + l4) ^ (row & 7);
        af[mf] = *(const bf16x8*)(ldsA + row * 128 + ch * 16);
      }
#pragma unroll
      for (int nf = 0; nf < 4; ++nf) {
        const int row = wn + nf * 16 + l15;
        const int ch = (ks * 4 + l4) ^ (row & 7);
        bfv[nf] = *(const bf16x8*)(ldsB + row * 128 + ch * 16);
      }
#pragma unroll
      for (int mf = 0; mf < 4; ++mf)
#pragma unroll
        for (int nf = 0; nf < 4; ++nf)
          acc[mf][nf] = __builtin_amdgcn_mfma_f32_16x16x32_bf16(af[mf], bfv[nf], acc[mf][nf], 0, 0, 0);
    }
  }

  if constexpr (EPI == 0) {
#pragma unroll
    for (int mf = 0; mf < 4; ++mf)
#pragma unroll
      for (int nf = 0; nf < 4; ++nf)
#pragma unroll
        for (int i = 0; i < 4; ++i) {
          const int row = m0 + wm + mf * 16 + l4 * 4 + i;  // D: row=(l>>4)*4+i, col=l&15
          const int col = n0 + wn + nf * 16 + l15;
          Cf[(size_t)row * Nn + col] = acc[mf][nf][i];
        }
  } else {
#pragma unroll
    for (int mf = 0; mf < 4; ++mf)
#pragma unroll
      for (int nf = 0; nf < 4; ++nf)
#pragma unroll
        for (int i = 0; i < 4; ++i) {
          const int row = m0 + wm + mf * 16 + l4 * 4 + i;  // 0..4095
          const int col = n0 + wn + nf * 16 + l15;         // 0..3071
          const int sel = col >> 10;
          const int wi = col & 1023;
          const int h = wi >> 6;
          const int d = wi & 63;
          const int b = row >> 11;
          const int t = row & 2047;
          float v = acc[mf][nf][i];
          if (sel == 0) v *= 0.125f;  // 1/sqrt(64), exact in bf16
          unsigned short* dst = (sel == 0) ? Qo : (sel == 1) ? Ko : Vo;
          dst[((size_t)(b * TH + h) * TT + t) * THD + d] = f2bu(v);
        }
  }
}

// ---------------- flash attention: block = (b, h, 64 q-rows), 2 waves x 32 rows ----------------
// K/V double-buffered in LDS; prefetch issued before compute, counted vmcnt + raw s_barrier
// (no __syncthreads in the loop: avoids the compiler's vmcnt(0) drain killing the prefetch).
__launch_bounds__(128)
__global__ void attn_kernel(const unsigned short* __restrict__ Qp, const unsigned short* __restrict__ Kp,
                            const unsigned short* __restrict__ Vt, unsigned short* __restrict__ Op) {
  __shared__ __align__(16) char smem[40960];
  // buf c (c=0,1): K at smem + c*16384  ([64 kv][64 d], 128B rows, chunk-XOR swizzled)
  //               V at smem + c*16384 + 8192  ([64 d][64 kv], same swizzle)
  const int tid = threadIdx.x;   // 128 threads
  const int lane = tid & 63;
  const int wave = tid >> 6;
  char* ldsP = smem + 32768 + wave * 4096;  // per-wave P [32][64] bf16, swizzled
  const int l15 = lane & 15, l4 = lane >> 4;

  const int qb = 31 - (int)blockIdx.x;  // heavy (long-row) blocks first
  const int h = blockIdx.y;
  const int b = blockIdx.z;
  const size_t headoff = (size_t)(b * TH + h) * TT * THD;
  const int q0 = qb * 64 + wave * 32;
  const int ntile = qb + 1;  // 64-kv tiles covering kv <= qb*64+63

  // Q fragments in registers (A-operand: lane holds Q[q0+mf*16+l15][ks*32 + l4*8 + j])
  bf16x8 aq[2][2];
#pragma unroll
  for (int mf = 0; mf < 2; ++mf)
#pragma unroll
    for (int ks = 0; ks < 2; ++ks)
      aq[mf][ks] = *(const bf16x8*)(Qp + headoff + (size_t)(q0 + mf * 16 + l15) * THD + ks * 32 + l4 * 8);

  f32x4 o[2][4];
  float mrun[2][4], lrun[2][4];
#pragma unroll
  for (int mf = 0; mf < 2; ++mf) {
#pragma unroll
    for (int nd = 0; nd < 4; ++nd) o[mf][nd] = (f32x4){0.f, 0.f, 0.f, 0.f};
#pragma unroll
    for (int i = 0; i < 4; ++i) { mrun[mf][i] = -3.0e38f; lrun[mf][i] = 0.f; }
  }

  // stage tile kt into buffer c: 8 global_load_lds per thread (4 K-chunks + 4 V-chunks)
  auto stage = [&](int kt, int c) {
    const int kv0 = kt * 64;
    char* bK = smem + c * 16384;
    char* bV = bK + 8192;
#pragma unroll
    for (int r = 0; r < 4; ++r) {
      const int cid = r * 128 + tid;   // 0..511 chunk id
      const int row = cid >> 3;
      const int srcc = (cid & 7) ^ (row & 7);
      gload_lds16(Kp + headoff + (size_t)(kv0 + row) * THD + srcc * 8, bK + (r * 128 + wave * 64) * 16);
      gload_lds16(Vt + headoff + (size_t)row * TT + kv0 + srcc * 8, bV + (r * 128 + wave * 64) * 16);
    }
  };

  int cur = 0;
  stage(0, 0);
  for (int kt = 0; kt < ntile; ++kt) {
    const int kv0 = kt * 64;
    // invariant: tile kt's loads (into buf cur) issued; all waves done reading buf cur^1
    if (kt + 1 < ntile) {
      stage(kt + 1, cur ^ 1);
      asm volatile("s_waitcnt vmcnt(8)" ::: "memory");  // kt's 8 loads retired; prefetch stays in flight
    } else {
      asm volatile("s_waitcnt vmcnt(0)" ::: "memory");
    }
    __builtin_amdgcn_s_barrier();       // all waves' kt loads visible in LDS
    __builtin_amdgcn_sched_barrier(0);  // pin: no LDS reads hoisted above the barrier
    char* ldsK = smem + cur * 16384;
    char* ldsV = ldsK + 8192;

    if (kv0 <= q0 + 31) {  // wave-uniform: skip compute on fully-masked tiles
      // S = Q K^T  (B-operand from K rows: lane holds K[nf*16+l15][k-chunk l4])
      f32x4 s[2][4];
#pragma unroll
      for (int mf = 0; mf < 2; ++mf)
#pragma unroll
        for (int nf = 0; nf < 4; ++nf) s[mf][nf] = (f32x4){0.f, 0.f, 0.f, 0.f};
#pragma unroll
      for (int ks = 0; ks < 2; ++ks) {
        bf16x8 bk[4];
#pragma unroll
        for (int nf = 0; nf < 4; ++nf) {
          const int row = nf * 16 + l15;
          const int ch = (ks * 4 + l4) ^ (row & 7);
          bk[nf] = *(const bf16x8*)(ldsK + row * 128 + ch * 16);
        }
#pragma unroll
        for (int mf = 0; mf < 2; ++mf)
#pragma unroll
          for (int nf = 0; nf < 4; ++nf)
            s[mf][nf] = __builtin_amdgcn_mfma_f32_16x16x32_bf16(aq[mf][ks], bk[nf], s[mf][nf], 0, 0, 0);
      }

      if (kv0 + 63 > q0) {  // causal mask needed for this tile
#pragma unroll
        for (int mf = 0; mf < 2; ++mf)
#pragma unroll
          for (int nf = 0; nf < 4; ++nf)
#pragma unroll
            for (int i = 0; i < 4; ++i) {
              const int rq = q0 + mf * 16 + l4 * 4 + i;
              const int ck = kv0 + nf * 16 + l15;
              if (ck > rq) s[mf][nf][i] = -3.0e38f;
            }
      }

      // online softmax; output row r lives in the 16 consecutive lanes sharing l>>4
      float mt[2][4], alpha[2][4], rs[2][4];
#pragma unroll
      for (int mf = 0; mf < 2; ++mf)
#pragma unroll
        for (int i = 0; i < 4; ++i) {
          float m = fmaxf(fmaxf(s[mf][0][i], s[mf][1][i]), fmaxf(s[mf][2][i], s[mf][3][i]));
#pragma unroll
          for (int d = 1; d < 16; d <<= 1) m = fmaxf(m, __shfl_xor(m, d));
          const float mn = fmaxf(mrun[mf][i], m);
          alpha[mf][i] = __expf(mrun[mf][i] - mn);
          mrun[mf][i] = mn;
          mt[mf][i] = mn;
          rs[mf][i] = 0.f;
        }
#pragma unroll
      for (int mf = 0; mf < 2; ++mf)
#pragma unroll
        for (int nf = 0; nf < 4; ++nf)
#pragma unroll
          for (int i = 0; i < 4; ++i) {
            const float p = __expf(s[mf][nf][i] - mt[mf][i]);
            rs[mf][i] += p;
            const int row = mf * 16 + l4 * 4 + i;
            const int col = nf * 16 + l15;
            *(unsigned short*)(ldsP + row * 128 + (((col >> 3) ^ (row & 7)) << 4) + ((col & 7) << 1)) = f2bu(p);
          }
#pragma unroll
      for (int mf = 0; mf < 2; ++mf)
#pragma unroll
        for (int i = 0; i < 4; ++i) {
#pragma unroll
          for (int d = 1; d < 16; d <<= 1) rs[mf][i] += __shfl_xor(rs[mf][i], d);
          lrun[mf][i] = lrun[mf][i] * alpha[mf][i] + rs[mf][i];
        }
#pragma unroll
      for (int mf = 0; mf < 2; ++mf)
#pragma unroll
        for (int nd = 0; nd < 4; ++nd)
#pragma unroll
          for (int i = 0; i < 4; ++i) o[mf][nd][i] *= alpha[mf][i];

      asm volatile("s_waitcnt lgkmcnt(0)" ::: "memory");  // P stores landed (same-wave buffer)

      // O += P V   (A from P_lds; B from ldsV rows = V^T rows, same pattern as K)
#pragma unroll
      for (int ks2 = 0; ks2 < 2; ++ks2) {
        bf16x8 pa[2];
#pragma unroll
        for (int mf = 0; mf < 2; ++mf) {
          const int row = mf * 16 + l15;
          const int ch = (ks2 * 4 + l4) ^ (row & 7);
          pa[mf] = *(const bf16x8*)(ldsP + row * 128 + ch * 16);
        }
#pragma unroll
        for (int nf = 0; nf < 4; ++nf) {
          const int row = nf * 16 + l15;  // d index
          const int ch = (ks2 * 4 + l4) ^ (row & 7);
          const bf16x8 bv = *(const bf16x8*)(ldsV + row * 128 + ch * 16);  // V[kv=ks2*32+l4*8+j][d=row]
#pragma unroll
          for (int mf = 0; mf < 2; ++mf)
            o[mf][nf] = __builtin_amdgcn_mfma_f32_16x16x32_bf16(pa[mf], bv, o[mf][nf], 0, 0, 0);
        }
      }
    }  // active-tile guard

    __builtin_amdgcn_s_barrier();  // all waves done reading buf cur -> next iter may prefetch into it
    cur ^= 1;
  }

  // epilogue: O normalized -> [b*T + t][h*64 + d] bf16
#pragma unroll
  for (int mf = 0; mf < 2; ++mf)
#pragma unroll
    for (int nd = 0; nd < 4; ++nd)
#pragma unroll
      for (int i = 0; i < 4; ++i) {
        const int row = q0 + mf * 16 + l4 * 4 + i;
        const int col = h * THD + nd * 16 + l15;
        Op[(size_t)(b * TT + row) * TC + col] = f2bu(o[mf][nd][i] / lrun[mf][i]);
      }
}

extern "C" void kernel_launch(void* const* d_in, const int* in_sizes, int n_in,
                              void* d_out, int out_size, void* d_ws, size_t ws_size,
                              hipStream_t stream) {
  (void)in_sizes; (void)n_in; (void)out_size; (void)ws_size;
  const float* x = (const float*)d_in[0];
  const float* wqkv = (const float*)d_in[1];
  const float* wout = (const float*)d_in[2];
  char* ws = (char*)d_ws;
  unsigned short* Xb = (unsigned short*)(ws);                          // [4096][1024] bf16, 8 MiB
  unsigned short* Wq = (unsigned short*)(ws + ((size_t)8 << 20));      // [3072][1024] bf16, 6 MiB
  unsigned short* Wo = (unsigned short*)(ws + ((size_t)14 << 20));     // [1024][1024] bf16, 2 MiB
  unsigned short* Qh = (unsigned short*)(ws + ((size_t)16 << 20));     // [b][h][t][d] bf16, 8 MiB
  unsigned short* Kh = (unsigned short*)(ws + ((size_t)24 << 20));
  unsigned short* Vh = (unsigned short*)(ws + ((size_t)32 << 20));
  unsigned short* Oh = (unsigned short*)(ws + ((size_t)40 << 20));     // [4096][1024] bf16
  unsigned short* Vtp = Xb;  // Xb slot is dead after the QKV GEMM; reuse for Vt [b][h][d][t]
  float* out = (float*)d_out;

  cast_bf16_kernel<<<2048, 256, 0, stream>>>(x, Xb, TM * TC / 8);
  transpose_cast_kernel<<<dim3(96, 32), dim3(32, 8), 0, stream>>>(wqkv, Wq, TC, 3 * TC);
  transpose_cast_kernel<<<dim3(32, 32), dim3(32, 8), 0, stream>>>(wout, Wo, TC, TC);
  gemm_bt_kernel<1><<<dim3(24, 32), 256, 0, stream>>>(Xb, Wq, nullptr, Qh, Kh, Vh, TM, 3 * TC, TC);
  transpose_v_kernel<<<dim3(32, 16, 2), 256, 0, stream>>>(Vh, Vtp);
  attn_kernel<<<dim3(32, 16, 2), 128, 0, stream>>>(Qh, Kh, Vtp, Oh);
  gemm_bt_kernel<0><<<dim3(8, 32), 256, 0, stream>>>(Oh, Wo, out, nullptr, nullptr, nullptr, TM, TC, TC);
}

// Round 5
// 238.849 us; speedup vs baseline: 1.0643x; 1.0643x over previous
//
#include <hip/hip_runtime.h>
#include <hip/hip_bf16.h>
#include <stdint.h>

typedef __bf16 bf16x8 __attribute__((ext_vector_type(8)));
typedef float  f32x4  __attribute__((ext_vector_type(4)));
typedef unsigned short ushort8 __attribute__((ext_vector_type(8)));

#define DEVI static __device__ __forceinline__

static constexpr int TB  = 2;     // batch
static constexpr int TT  = 2048;  // seq len
static constexpr int TC  = 1024;  // d_model
static constexpr int TH  = 16;    // heads
static constexpr int THD = 64;    // head dim
static constexpr int TM  = TB * TT;  // 4096 flattened rows

DEVI unsigned short f2bu(float f) {
  union { float f; unsigned u; } v; v.f = f;
  unsigned u = v.u;
  return (unsigned short)((u + 0x7FFFu + ((u >> 16) & 1u)) >> 16);
}

DEVI void gload_lds16(const unsigned short* g, char* l) {
  __builtin_amdgcn_global_load_lds((const __attribute__((address_space(1))) void*)g,
                                   (__attribute__((address_space(3))) void*)l, 16, 0, 0);
}

// ---------------- cast fp32 -> bf16 (8 elems/thread) ----------------
__global__ void cast_bf16_kernel(const float* __restrict__ in, unsigned short* __restrict__ out, int n8) {
  int i = blockIdx.x * blockDim.x + threadIdx.x;
  if (i >= n8) return;
  float4 a = ((const float4*)in)[2 * i];
  float4 b = ((const float4*)in)[2 * i + 1];
  ushort8 r;
  r[0] = f2bu(a.x); r[1] = f2bu(a.y); r[2] = f2bu(a.z); r[3] = f2bu(a.w);
  r[4] = f2bu(b.x); r[5] = f2bu(b.y); r[6] = f2bu(b.z); r[7] = f2bu(b.w);
  ((ushort8*)out)[i] = r;
}

// ------------- transpose + cast: in fp32 [R][Cc] -> out bf16 [Cc][R] -------------
__global__ void transpose_cast_kernel(const float* __restrict__ in, unsigned short* __restrict__ out,
                                      int R, int Cc) {
  __shared__ float tile[32][33];
  const int c0 = blockIdx.x * 32, r0 = blockIdx.y * 32;
  const int tx = threadIdx.x, ty = threadIdx.y;  // (32, 8)
#pragma unroll
  for (int i = 0; i < 4; ++i)
    tile[ty + i * 8][tx] = in[(size_t)(r0 + ty + i * 8) * Cc + c0 + tx];
  __syncthreads();
#pragma unroll
  for (int i = 0; i < 4; ++i)
    out[(size_t)(c0 + ty + i * 8) * R + r0 + tx] = f2bu(tile[tx][ty + i * 8]);
}

// ------------- per-head V transpose: Vh[b][h][t][d] -> Vt[b][h][d][t] (bf16) -------------
__global__ void transpose_v_kernel(const unsigned short* __restrict__ Vh, unsigned short* __restrict__ Vt) {
  __shared__ unsigned short tile[64][72];  // 64 t-rows x 64 d-cols, padded row (144B)
  const int t0 = blockIdx.x * 64;
  const size_t ho = (size_t)(blockIdx.z * TH + blockIdx.y) * TT * THD;
  const int tid = threadIdx.x;  // 256
#pragma unroll
  for (int it = 0; it < 2; ++it) {
    const int r = it * 32 + (tid >> 3), c8 = tid & 7;
    *(ushort8*)&tile[r][c8 * 8] = *(const ushort8*)(Vh + ho + (size_t)(t0 + r) * THD + c8 * 8);
  }
  __syncthreads();
  const int d = tid >> 2, tc = tid & 3;
  ushort8 a, b;
#pragma unroll
  for (int j = 0; j < 8; ++j) a[j] = tile[tc * 16 + j][d];
#pragma unroll
  for (int j = 0; j < 8; ++j) b[j] = tile[tc * 16 + 8 + j][d];
  *(ushort8*)(Vt + ho + (size_t)d * TT + t0 + tc * 16) = a;
  *(ushort8*)(Vt + ho + (size_t)d * TT + t0 + tc * 16 + 8) = b;
}

// ---------------- GEMM: A[M][K] @ Bt[N][K]^T, bf16 MFMA, 128x128 tile ----------------
// EPI==0: write fp32 C[M][N].  EPI==1: scatter qkv -> per-head Q(,*0.125)/K/V [b][h][t][d].
template <int EPI>
__launch_bounds__(256)
__global__ void gemm_bt_kernel(const unsigned short* __restrict__ A, const unsigned short* __restrict__ Bt,
                               float* __restrict__ Cf,
                               unsigned short* __restrict__ Qo, unsigned short* __restrict__ Ko,
                               unsigned short* __restrict__ Vo,
                               int Mm, int Nn, int Kk) {
  __shared__ __align__(16) char smem[32768];
  char* ldsA = smem;
  char* ldsB = smem + 16384;
  const int tid = threadIdx.x;
  const int lane = tid & 63;
  const int wave = tid >> 6;
  const int l15 = lane & 15, l4 = lane >> 4;
  const int m0 = blockIdx.y * 128;
  const int n0 = blockIdx.x * 128;
  const int wm = (wave >> 1) * 64;
  const int wn = (wave & 1) * 64;

  f32x4 acc[4][4];
#pragma unroll
  for (int a = 0; a < 4; ++a)
#pragma unroll
    for (int b = 0; b < 4; ++b) acc[a][b] = (f32x4){0.f, 0.f, 0.f, 0.f};

  const int nk = Kk >> 6;
  for (int kt = 0; kt < nk; ++kt) {
    __syncthreads();  // previous tile fully consumed
#pragma unroll
    for (int r = 0; r < 4; ++r) {
      // LDS chunk cid holds global k-chunk (cid&7)^(row&7)  (XOR swizzle via pre-permuted source)
      const int cid = r * 256 + tid;
      const int row = cid >> 3;
      const int srcc = (cid & 7) ^ (row & 7);
      gload_lds16(A + (size_t)(m0 + row) * Kk + kt * 64 + srcc * 8, ldsA + (r * 256 + wave * 64) * 16);
      gload_lds16(Bt + (size_t)(n0 + row) * Kk + kt * 64 + srcc * 8, ldsB + (r * 256 + wave * 64) * 16);
    }
    __syncthreads();  // drains vmcnt -> tiles resident
#pragma unroll
    for (int ks = 0; ks < 2; ++ks) {
      bf16x8 af[4], bfv[4];
#pragma unroll
      for (int mf = 0; mf < 4; ++mf) {
        const int row = wm + mf * 16 + l15;
        const int ch = (ks * 4 + l4) ^ (row & 7);
        af[mf] = *(const bf16x8*)(ldsA + row * 128 + ch * 16);
      }
#pragma unroll
      for (int nf = 0; nf < 4; ++nf) {
        const int row = wn + nf * 16 + l15;
        const int ch = (ks * 4 + l4) ^ (row & 7);
        bfv[nf] = *(const bf16x8*)(ldsB + row * 128 + ch * 16);
      }
#pragma unroll
      for (int mf = 0; mf < 4; ++mf)
#pragma unroll
        for (int nf = 0; nf < 4; ++nf)
          acc[mf][nf] = __builtin_amdgcn_mfma_f32_16x16x32_bf16(af[mf], bfv[nf], acc[mf][nf], 0, 0, 0);
    }
  }

  if constexpr (EPI == 0) {
#pragma unroll
    for (int mf = 0; mf < 4; ++mf)
#pragma unroll
      for (int nf = 0; nf < 4; ++nf)
#pragma unroll
        for (int i = 0; i < 4; ++i) {
          const int row = m0 + wm + mf * 16 + l4 * 4 + i;  // D: row=(l>>4)*4+i, col=l&15
          const int col = n0 + wn + nf * 16 + l15;
          Cf[(size_t)row * Nn + col] = acc[mf][nf][i];
        }
  } else {
#pragma unroll
    for (int mf = 0; mf < 4; ++mf)
#pragma unroll
      for (int nf = 0; nf < 4; ++nf)
#pragma unroll
        for (int i = 0; i < 4; ++i) {
          const int row = m0 + wm + mf * 16 + l4 * 4 + i;  // 0..4095
          const int col = n0 + wn + nf * 16 + l15;         // 0..3071
          const int sel = col >> 10;
          const int wi = col & 1023;
          const int h = wi >> 6;
          const int d = wi & 63;
          const int b = row >> 11;
          const int t = row & 2047;
          float v = acc[mf][nf][i];
          if (sel == 0) v *= 0.125f;  // 1/sqrt(64), exact in bf16
          unsigned short* dst = (sel == 0) ? Qo : (sel == 1) ? Ko : Vo;
          dst[((size_t)(b * TH + h) * TT + t) * THD + d] = f2bu(v);
        }
  }
}

// ---------------- flash attention: block = (b, h, heavy/light q-tile pair), 4 waves ----------------
// Waves 0,1 own heavy q-tile qA (64 rows); waves 2,3 own light q-tile qB=31-qA.
// One shared K/V staging stream (qA+1 tiles) serves both (light's tiles are a prefix).
// Per-block compute = 66 wave-tiles, constant -> perfect CU load balance.
// K/V double-buffered; prefetch + counted vmcnt + raw s_barrier (no __syncthreads drain).
__launch_bounds__(256)
__global__ void attn_kernel(const unsigned short* __restrict__ Qp, const unsigned short* __restrict__ Kp,
                            const unsigned short* __restrict__ Vt, unsigned short* __restrict__ Op) {
  __shared__ __align__(16) char smem[49152];
  // buf c (c=0,1): K at smem + c*16384  ([64 kv][64 d], 128B rows, chunk-XOR swizzled)
  //               V at smem + c*16384 + 8192  ([64 d][64 kv], same swizzle)
  const int tid = threadIdx.x;   // 256 threads
  const int lane = tid & 63;
  const int wave = tid >> 6;
  char* ldsP = smem + 32768 + wave * 4096;  // per-wave P [32][64] bf16, swizzled
  const int l15 = lane & 15, l4 = lane >> 4;

  const int h = blockIdx.y;
  const int b = blockIdx.z;
  // bxe^15 on half the grid -> each CU's two resident blocks have qA1+qA2 = 47 (balanced staging)
  const int bxe = (int)blockIdx.x ^ (b ? 15 : 0);
  const int qA = 31 - bxe;       // heavy q-tile (16..31)
  const int qB = bxe;            // light q-tile (= 31 - qA)
  const size_t headoff = (size_t)(b * TH + h) * TT * THD;
  const int qt = (wave >> 1) ? qB : qA;
  const int q0 = qt * 64 + (wave & 1) * 32;
  const int ntile = qA + 1;      // staging covers the heavy member's causal range

  // Q fragments in registers (A-operand: lane holds Q[q0+mf*16+l15][ks*32 + l4*8 + j])
  bf16x8 aq[2][2];
#pragma unroll
  for (int mf = 0; mf < 2; ++mf)
#pragma unroll
    for (int ks = 0; ks < 2; ++ks)
      aq[mf][ks] = *(const bf16x8*)(Qp + headoff + (size_t)(q0 + mf * 16 + l15) * THD + ks * 32 + l4 * 8);

  f32x4 o[2][4];
  float mrun[2][4], lrun[2][4];
#pragma unroll
  for (int mf = 0; mf < 2; ++mf) {
#pragma unroll
    for (int nd = 0; nd < 4; ++nd) o[mf][nd] = (f32x4){0.f, 0.f, 0.f, 0.f};
#pragma unroll
    for (int i = 0; i < 4; ++i) { mrun[mf][i] = -3.0e38f; lrun[mf][i] = 0.f; }
  }

  // stage tile kt into buffer c: 4 global_load_lds per thread (2 K-chunks + 2 V-chunks)
  auto stage = [&](int kt, int c) {
    const int kv0 = kt * 64;
    char* bK = smem + c * 16384;
    char* bV = bK + 8192;
#pragma unroll
    for (int r = 0; r < 2; ++r) {
      const int cid = r * 256 + tid;   // 0..511 chunk id
      const int row = cid >> 3;
      const int srcc = (cid & 7) ^ (row & 7);
      gload_lds16(Kp + headoff + (size_t)(kv0 + row) * THD + srcc * 8, bK + (r * 256 + wave * 64) * 16);
      gload_lds16(Vt + headoff + (size_t)row * TT + kv0 + srcc * 8, bV + (r * 256 + wave * 64) * 16);
    }
  };

  int cur = 0;
  stage(0, 0);
  for (int kt = 0; kt < ntile; ++kt) {
    const int kv0 = kt * 64;
    // invariant: tile kt's loads (into buf cur) issued; all waves done reading buf cur^1
    if (kt + 1 < ntile) {
      stage(kt + 1, cur ^ 1);
      asm volatile("s_waitcnt vmcnt(4)" ::: "memory");  // kt's 4 loads retired; prefetch stays in flight
    } else {
      asm volatile("s_waitcnt vmcnt(0)" ::: "memory");
    }
    __builtin_amdgcn_s_barrier();       // all waves' kt loads visible in LDS
    __builtin_amdgcn_sched_barrier(0);  // pin: no LDS reads hoisted above the barrier
    char* ldsK = smem + cur * 16384;
    char* ldsV = ldsK + 8192;

    if (kv0 <= q0 + 31) {  // wave-uniform: light waves idle on tiles beyond their causal range
      // S = Q K^T  (B-operand from K rows: lane holds K[nf*16+l15][k-chunk l4])
      f32x4 s[2][4];
#pragma unroll
      for (int mf = 0; mf < 2; ++mf)
#pragma unroll
        for (int nf = 0; nf < 4; ++nf) s[mf][nf] = (f32x4){0.f, 0.f, 0.f, 0.f};
#pragma unroll
      for (int ks = 0; ks < 2; ++ks) {
        bf16x8 bk[4];
#pragma unroll
        for (int nf = 0; nf < 4; ++nf) {
          const int row = nf * 16 + l15;
          const int ch = (ks * 4 + l4) ^ (row & 7);
          bk[nf] = *(const bf16x8*)(ldsK + row * 128 + ch * 16);
        }
#pragma unroll
        for (int mf = 0; mf < 2; ++mf)
#pragma unroll
          for (int nf = 0; nf < 4; ++nf)
            s[mf][nf] = __builtin_amdgcn_mfma_f32_16x16x32_bf16(aq[mf][ks], bk[nf], s[mf][nf], 0, 0, 0);
      }

      if (kv0 + 63 > q0) {  // causal mask needed for this tile
#pragma unroll
        for (int mf = 0; mf < 2; ++mf)
#pragma unroll
          for (int nf = 0; nf < 4; ++nf)
#pragma unroll
            for (int i = 0; i < 4; ++i) {
              const int rq = q0 + mf * 16 + l4 * 4 + i;
              const int ck = kv0 + nf * 16 + l15;
              if (ck > rq) s[mf][nf][i] = -3.0e38f;
            }
      }

      // online softmax; output row r lives in the 16 consecutive lanes sharing l>>4
      float mt[2][4], alpha[2][4], rs[2][4];
#pragma unroll
      for (int mf = 0; mf < 2; ++mf)
#pragma unroll
        for (int i = 0; i < 4; ++i) {
          float m = fmaxf(fmaxf(s[mf][0][i], s[mf][1][i]), fmaxf(s[mf][2][i], s[mf][3][i]));
#pragma unroll
          for (int d = 1; d < 16; d <<= 1) m = fmaxf(m, __shfl_xor(m, d));
          const float mn = fmaxf(mrun[mf][i], m);
          alpha[mf][i] = __expf(mrun[mf][i] - mn);
          mrun[mf][i] = mn;
          mt[mf][i] = mn;
          rs[mf][i] = 0.f;
        }
#pragma unroll
      for (int mf = 0; mf < 2; ++mf)
#pragma unroll
        for (int nf = 0; nf < 4; ++nf)
#pragma unroll
          for (int i = 0; i < 4; ++i) {
            const float p = __expf(s[mf][nf][i] - mt[mf][i]);
            rs[mf][i] += p;
            const int row = mf * 16 + l4 * 4 + i;
            const int col = nf * 16 + l15;
            *(unsigned short*)(ldsP + row * 128 + (((col >> 3) ^ (row & 7)) << 4) + ((col & 7) << 1)) = f2bu(p);
          }
#pragma unroll
      for (int mf = 0; mf < 2; ++mf)
#pragma unroll
        for (int i = 0; i < 4; ++i) {
#pragma unroll
          for (int d = 1; d < 16; d <<= 1) rs[mf][i] += __shfl_xor(rs[mf][i], d);
          lrun[mf][i] = lrun[mf][i] * alpha[mf][i] + rs[mf][i];
        }
#pragma unroll
      for (int mf = 0; mf < 2; ++mf)
#pragma unroll
        for (int nd = 0; nd < 4; ++nd)
#pragma unroll
          for (int i = 0; i < 4; ++i) o[mf][nd][i] *= alpha[mf][i];

      asm volatile("s_waitcnt lgkmcnt(0)" ::: "memory");  // P stores landed (same-wave buffer)

      // O += P V   (A from P_lds; B from ldsV rows = V^T rows, same pattern as K)
#pragma unroll
      for (int ks2 = 0; ks2 < 2; ++ks2) {
        bf16x8 pa[2];
#pragma unroll
        for (int mf = 0; mf < 2; ++mf) {
          const int row = mf * 16 + l15;
          const int ch = (ks2 * 4 + l4) ^ (row & 7);
          pa[mf] = *(const bf16x8*)(ldsP + row * 128 + ch * 16);
        }
#pragma unroll
        for (int nf = 0; nf < 4; ++nf) {
          const int row = nf * 16 + l15;  // d index
          const int ch = (ks2 * 4 + l4) ^ (row & 7);
          const bf16x8 bv = *(const bf16x8*)(ldsV + row * 128 + ch * 16);  // V[kv=ks2*32+l4*8+j][d=row]
#pragma unroll
          for (int mf = 0; mf < 2; ++mf)
            o[mf][nf] = __builtin_amdgcn_mfma_f32_16x16x32_bf16(pa[mf], bv, o[mf][nf], 0, 0, 0);
        }
      }
    }  // active-tile guard

    __builtin_amdgcn_s_barrier();  // all waves done reading buf cur -> next iter may prefetch into it
    cur ^= 1;
  }

  // epilogue: O normalized -> [b*T + t][h*64 + d] bf16
#pragma unroll
  for (int mf = 0; mf < 2; ++mf)
#pragma unroll
    for (int nd = 0; nd < 4; ++nd)
#pragma unroll
      for (int i = 0; i < 4; ++i) {
        const int row = q0 + mf * 16 + l4 * 4 + i;
        const int col = h * THD + nd * 16 + l15;
        Op[(size_t)(b * TT + row) * TC + col] = f2bu(o[mf][nd][i] / lrun[mf][i]);
      }
}

extern "C" void kernel_launch(void* const* d_in, const int* in_sizes, int n_in,
                              void* d_out, int out_size, void* d_ws, size_t ws_size,
                              hipStream_t stream) {
  (void)in_sizes; (void)n_in; (void)out_size; (void)ws_size;
  const float* x = (const float*)d_in[0];
  const float* wqkv = (const float*)d_in[1];
  const float* wout = (const float*)d_in[2];
  char* ws = (char*)d_ws;
  unsigned short* Xb = (unsigned short*)(ws);                          // [4096][1024] bf16, 8 MiB
  unsigned short* Wq = (unsigned short*)(ws + ((size_t)8 << 20));      // [3072][1024] bf16, 6 MiB
  unsigned short* Wo = (unsigned short*)(ws + ((size_t)14 << 20));     // [1024][1024] bf16, 2 MiB
  unsigned short* Qh = (unsigned short*)(ws + ((size_t)16 << 20));     // [b][h][t][d] bf16, 8 MiB
  unsigned short* Kh = (unsigned short*)(ws + ((size_t)24 << 20));
  unsigned short* Vh = (unsigned short*)(ws + ((size_t)32 << 20));
  unsigned short* Oh = (unsigned short*)(ws + ((size_t)40 << 20));     // [4096][1024] bf16
  unsigned short* Vtp = Xb;  // Xb slot is dead after the QKV GEMM; reuse for Vt [b][h][d][t]
  float* out = (float*)d_out;

  cast_bf16_kernel<<<2048, 256, 0, stream>>>(x, Xb, TM * TC / 8);
  transpose_cast_kernel<<<dim3(96, 32), dim3(32, 8), 0, stream>>>(wqkv, Wq, TC, 3 * TC);
  transpose_cast_kernel<<<dim3(32, 32), dim3(32, 8), 0, stream>>>(wout, Wo, TC, TC);
  gemm_bt_kernel<1><<<dim3(24, 32), 256, 0, stream>>>(Xb, Wq, nullptr, Qh, Kh, Vh, TM, 3 * TC, TC);
  transpose_v_kernel<<<dim3(32, 16, 2), 256, 0, stream>>>(Vh, Vtp);
  attn_kernel<<<dim3(16, 16, 2), 256, 0, stream>>>(Qh, Kh, Vtp, Oh);
  gemm_bt_kernel<0><<<dim3(8, 32), 256, 0, stream>>>(Oh, Wo, out, nullptr, nullptr, nullptr, TM, TC, TC);
}